// Round 11
// baseline (144.255 us; speedup 1.0000x reference)
//
#include <hip/hip_runtime.h>

// Problem constants (from reference): B=16, C=1, H=1024, W=1024, fp32.
#define HH 1024
#define WW 1024
#define BAND 8            // output rows per block
#define NT 1024           // threads per block (16 waves)
#define TROWS (BAND + 2)  // staged target rows (with vertical halo)
#define LDS_T (TROWS * WW)         // 10240 floats = 40960 B
#define LDS_P (BAND * WW)          // 8192  floats = 32768 B

__device__ __forceinline__ float fmax3(float a, float b, float c) {
    return fmaxf(a, fmaxf(b, c));
}

__device__ __forceinline__ float loss_elem(float x, float t, float dil) {
    // target/dilated are exactly binary {0,1}: weight = 1 + 4*dil + 15*t
    float w = fmaf(15.0f, t, fmaf(4.0f, dil, 1.0f));
    // BCE with logits: max(x,0) - x*t + log1p(exp(-|x|))
    // softplus via HW v_exp_f32 / v_log_f32 (absmax 0.0 since R2).
    float a  = fabsf(x);
    float sp = __logf(1.0f + __expf(-a));
    return w * (fmaxf(x, 0.0f) - x * t + sp);
}

__device__ __forceinline__ void dma16(const float* g, float* l) {
    // async global->LDS, 16B/lane; dest = wave-uniform base + lane*16.
    // Flat contiguous layout (lds idx == source idx) satisfies that.
    __builtin_amdgcn_global_load_lds(
        (const __attribute__((address_space(1))) void*)g,
        (__attribute__((address_space(3))) void*)l,
        16, 0, 0);
}

template <bool PER_WAVE>
__global__ __launch_bounds__(NT) void dilatedweightBCE_main(
        const float* __restrict__ pred,
        const float* __restrict__ target,
        float* __restrict__ partial) {
    // ALL global traffic is fire-and-forget LDS-DMA (zero result VGPRs, no
    // dependency until the one barrier): 3 target chunks + 2 pred chunks per
    // thread. R4-R10 showed VGPR-carried loads cap outstanding requests
    // (compiler serializes them; plateau 3.3-4.8 TB/s requested). Compute
    // phase is pure LDS. 72KB LDS -> 2 blocks/CU = 32 waves/CU (HW max).
    __shared__ float ldsT[LDS_T];   // target rows h0-1 .. h0+BAND
    __shared__ float ldsP[LDS_P];   // pred rows h0 .. h0+BAND-1

    const int t    = threadIdx.x;
    const int lane = t & 63;
    const int wv   = t >> 6;                 // wave id 0..15

    // --- XCD-contiguous swizzle: each XCD owns a 128-row slab per image ---
    const int l    = blockIdx.x;             // [0, 2048)
    const int xcd  = l & 7;
    const int j    = l >> 3;                 // [0, 256)
    const int img  = j >> 4;                 // [0, 16)
    const int band = j & 15;                 // [0, 16)
    const int h0   = (xcd * 16 + band) * BAND;

    const float* timg = target + (size_t)img * HH * WW;
    const float* pimg = pred   + (size_t)img * HH * WW;

    // ---- zero-fill out-of-image halo rows (wave-uniform, disjoint of DMA) ----
    const float4 zero4 = make_float4(0.0f, 0.0f, 0.0f, 0.0f);
    if (h0 == 0 && t < 256) ((float4*)ldsT)[t] = zero4;                  // row 0
    if (h0 + BAND == HH && t >= 256 && t < 512)
        ((float4*)ldsT)[2048 + t] = zero4;                               // row 9

    // ---- target staging: 2560 float4 in 3 chunks (all guards wave-uniform) ----
    const float* srcT = timg + (long long)(h0 - 1) * WW;   // row h0-1 base
    {
        // chunk 0: idx t (rows 0..3); row 0 invalid iff h0==0 (waves 0..3)
        if (!(h0 == 0 && t < 256))
            dma16(srcT + (size_t)t * 4, ldsT + (size_t)t * 4);
        // chunk 1: idx 1024+t (rows 4..7), always valid
        dma16(srcT + (size_t)(1024 + t) * 4, ldsT + (size_t)(1024 + t) * 4);
        // chunk 2: idx 2048+t for t<512 (rows 8..9); row 9 invalid iff last band
        if (t < 512 && !(h0 + BAND == HH && t >= 256))
            dma16(srcT + (size_t)(2048 + t) * 4, ldsT + (size_t)(2048 + t) * 4);
    }
    // ---- pred staging: 2048 float4 in 2 chunks ----
    {
        const float* srcP = pimg + (size_t)h0 * WW;
        dma16(srcP + (size_t)t * 4,          ldsP + (size_t)t * 4);
        dma16(srcP + (size_t)(1024 + t) * 4, ldsP + (size_t)(1024 + t) * 4);
    }

    __syncthreads();   // drains vmcnt(0) + lgkmcnt(0): staging complete

    // ---- compute: thread owns 2 output rows x one float4 strip ----
    const int strip = t & 255;
    const int c     = strip * 4;             // first column
    const int rp    = t >> 8;                // row pair 0..3 (wave-uniform)
    const int o0    = rp * 2;                // first output row (lds-relative +1)

    // target lds rows o0 .. o0+3 cover outputs o0, o0+1
    float4 T0 = *(const float4*)(ldsT + (o0    ) * WW + c);
    float4 T1 = *(const float4*)(ldsT + (o0 + 1) * WW + c);
    float4 T2 = *(const float4*)(ldsT + (o0 + 2) * WW + c);
    float4 T3 = *(const float4*)(ldsT + (o0 + 3) * WW + c);
    float4 X0 = *(const float4*)(ldsP + (o0    ) * WW + c);
    float4 X1 = *(const float4*)(ldsP + (o0 + 1) * WW + c);

    // horizontal halo columns from LDS (2 active lanes/wave, LDS-only)
    float hl[2] = {0.0f, 0.0f};
    if (lane == 0 || lane == 63) {
        const int pc = (lane == 0) ? c - 1 : c + 4;
        if (pc >= 0 && pc < WW) {
            float h0v = ldsT[(o0    ) * WW + pc];
            float h1v = ldsT[(o0 + 1) * WW + pc];
            float h2v = ldsT[(o0 + 2) * WW + pc];
            float h3v = ldsT[(o0 + 3) * WW + pc];
            hl[0] = fmax3(h0v, h1v, h2v);
            hl[1] = fmax3(h1v, h2v, h3v);
        }
    }

    float s = 0.0f;
    #pragma unroll
    for (int k = 0; k < 2; ++k) {
        float4 a = (k == 0) ? T0 : T1;
        float4 m = (k == 0) ? T1 : T2;
        float4 d = (k == 0) ? T2 : T3;
        float4 x = (k == 0) ? X0 : X1;

        float4 vm = make_float4(fmax3(a.x, m.x, d.x), fmax3(a.y, m.y, d.y),
                                fmax3(a.z, m.z, d.z), fmax3(a.w, m.w, d.w));

        float lft = __shfl_up(vm.w, 1);
        float rgt = __shfl_down(vm.x, 1);
        if (lane == 0)  lft = hl[k];
        if (lane == 63) rgt = hl[k];

        float d0 = fmax3(lft,  vm.x, vm.y);
        float d1 = fmax3(vm.x, vm.y, vm.z);
        float d2 = fmax3(vm.y, vm.z, vm.w);
        float d3 = fmax3(vm.z, vm.w, rgt);

        s += loss_elem(x.x, m.x, d0);
        s += loss_elem(x.y, m.y, d1);
        s += loss_elem(x.z, m.z, d2);
        s += loss_elem(x.w, m.w, d3);
    }

    // ---- wave reduction ----
    #pragma unroll
    for (int off = 32; off > 0; off >>= 1)
        s += __shfl_down(s, off);

    if (PER_WAVE) {
        if (lane == 0) partial[(size_t)l * 16 + wv] = s;  // no extra barrier
    } else {
        __syncthreads();                 // staging LDS is dead; reuse it
        if (lane == 0) ldsT[wv] = s;
        __syncthreads();
        if (t == 0) {
            float tot = 0.0f;
            #pragma unroll
            for (int i = 0; i < 16; ++i) tot += ldsT[i];
            partial[l] = tot;
        }
    }
}

__global__ __launch_bounds__(1024) void dilatedweightBCE_reduce(
        const float* __restrict__ partial,
        float* __restrict__ out,
        int npart4,            // number of float4 chunks
        float inv_n) {
    __shared__ float swave[16];
    const int t = threadIdx.x;

    float s = 0.0f;
    const float4* p4 = (const float4*)partial;
    for (int i = t; i < npart4; i += 1024) {
        float4 v = p4[i];
        s += v.x + v.y + v.z + v.w;
    }

    #pragma unroll
    for (int off = 32; off > 0; off >>= 1)
        s += __shfl_down(s, off);

    const int lane = t & 63;
    if (lane == 0) swave[t >> 6] = s;
    __syncthreads();
    if (t == 0) {
        float tot = 0.0f;
        #pragma unroll
        for (int i = 0; i < 16; ++i) tot += swave[i];
        out[0] = tot * inv_n;
    }
}

extern "C" void kernel_launch(void* const* d_in, const int* in_sizes, int n_in,
                              void* d_out, int out_size, void* d_ws, size_t ws_size,
                              hipStream_t stream) {
    const float* pred   = (const float*)d_in[0];
    const float* target = (const float*)d_in[1];
    float* out     = (float*)d_out;
    float* partial = (float*)d_ws;

    const int n  = in_sizes[0];              // B*C*H*W
    const int Bn = n / (HH * WW);            // batch (16)
    const int nblocks = (HH / BAND) * Bn;    // 2048

    const size_t need = (size_t)nblocks * 16 * sizeof(float);  // 128 KB
    if (ws_size >= need) {
        dilatedweightBCE_main<true><<<nblocks, NT, 0, stream>>>(pred, target, partial);
        dilatedweightBCE_reduce<<<1, 1024, 0, stream>>>(partial, out,
                                                        nblocks * 16 / 4,
                                                        1.0f / (float)n);
    } else {
        dilatedweightBCE_main<false><<<nblocks, NT, 0, stream>>>(pred, target, partial);
        dilatedweightBCE_reduce<<<1, 1024, 0, stream>>>(partial, out,
                                                        nblocks / 4,
                                                        1.0f / (float)n);
    }
}